// Round 1
// baseline (960.479 us; speedup 1.0000x reference)
//
#include <hip/hip_runtime.h>
#include <math.h>

// ---------------- CSR build ----------------

__global__ void hist_kernel(const int* __restrict__ dst, int E, int* __restrict__ cnt) {
    int e = blockIdx.x * blockDim.x + threadIdx.x;
    if (e < E) atomicAdd(&cnt[dst[e]], 1);
}

// wave-scan segment allocation + dinv = rsqrt(deg+1)
__global__ void alloc_kernel(const int* __restrict__ cnt, int* __restrict__ row_start,
                             float* __restrict__ dinv, int* __restrict__ total, int N) {
    int i = blockIdx.x * blockDim.x + threadIdx.x;
    int lane = threadIdx.x & 63;
    int c = (i < N) ? cnt[i] : 0;
    int inc = c;
#pragma unroll
    for (int o = 1; o < 64; o <<= 1) {
        int v = __shfl_up(inc, o, 64);
        if (lane >= o) inc += v;
    }
    int wsum = __shfl(inc, 63, 64);
    int base = 0;
    if (lane == 0) base = atomicAdd(total, wsum);
    base = __shfl(base, 0, 64);
    if (i < N) {
        row_start[i] = base + inc - c;
        dinv[i] = rsqrtf((float)(c + 1));
    }
}

__global__ void scatter_kernel(const int* __restrict__ src, const int* __restrict__ dst, int E,
                               const int* __restrict__ row_start, int* __restrict__ cursor,
                               int* __restrict__ csr) {
    int e = blockIdx.x * blockDim.x + threadIdx.x;
    if (e < E) {
        int d = dst[e];
        int p = row_start[d] + atomicAdd(&cursor[d], 1);
        csr[p] = src[e];
    }
}

// ---------------- GEMM1: xw1 = x @ W1   (N x 512) @ (512 x 64) ----------------
// block = 256 threads = 256 nodes. x tile staged TRANSPOSED in LDS [32 k][257 pad].
// W row address is wave-uniform -> scalar loads; inner loop ~= 1 ds_read + 64 FMA.
__global__ __launch_bounds__(256, 4) void gemm1_kernel(const float* __restrict__ x,
                                                       const float* __restrict__ W,
                                                       float* __restrict__ out, int N) {
    __shared__ float xs[32 * 257];
    const int tid = threadIdx.x;
    const int nodeBase = blockIdx.x * 256;

    float acc[64];
#pragma unroll
    for (int c = 0; c < 64; c++) acc[c] = 0.f;

    for (int kc = 0; kc < 512; kc += 32) {
        __syncthreads();
#pragma unroll
        for (int i = 0; i < 8; i++) {
            int f4 = tid + i * 256;       // 0..2047
            int node = f4 >> 3;           // 0..255
            int kp = (f4 & 7) * 4;        // 0,4,..,28
            int gn = nodeBase + node;
            if (gn >= N) gn = N - 1;
            const float4 v = *(const float4*)(x + (size_t)gn * 512 + kc + kp);
            xs[(kp + 0) * 257 + node] = v.x;
            xs[(kp + 1) * 257 + node] = v.y;
            xs[(kp + 2) * 257 + node] = v.z;
            xs[(kp + 3) * 257 + node] = v.w;
        }
        __syncthreads();
        const float* Wk = W + (size_t)kc * 64;
#pragma unroll 4
        for (int k = 0; k < 32; k++) {
            float xv = xs[k * 257 + tid];
            const float* wrow = Wk + k * 64;   // uniform address -> s_load
#pragma unroll
            for (int c = 0; c < 64; c++)
                acc[c] = fmaf(xv, wrow[c], acc[c]);
        }
    }
    int myNode = nodeBase + tid;
    if (myNode < N) {
        float4* dst4 = (float4*)(out + (size_t)myNode * 64);
#pragma unroll
        for (int c = 0; c < 16; c++)
            dst4[c] = make_float4(acc[4 * c], acc[4 * c + 1], acc[4 * c + 2], acc[4 * c + 3]);
    }
}

// ---------------- 64-dim CSR aggregation (one wave per node, lane = feature) ----------------
template <int RELU, int BIAS>
__global__ void agg64_kernel(const float* __restrict__ in, float* __restrict__ out,
                             const int* __restrict__ row_start, const int* __restrict__ cnt,
                             const int* __restrict__ csr, const float* __restrict__ dinv,
                             const float* __restrict__ bias, int N) {
    int gw = (int)((blockIdx.x * (size_t)blockDim.x + threadIdx.x) >> 6);
    int lane = threadIdx.x & 63;
    if (gw >= N) return;
    float di = dinv[gw];
    float acc = di * di * in[(size_t)gw * 64 + lane];   // self loop
    int s = row_start[gw];
    int c = cnt[gw];
    int e = 0;
    for (; e + 4 <= c; e += 4) {   // 4 gathers in flight for latency hiding
        int j0 = csr[s + e + 0], j1 = csr[s + e + 1], j2 = csr[s + e + 2], j3 = csr[s + e + 3];
        float w0 = dinv[j0], w1 = dinv[j1], w2 = dinv[j2], w3 = dinv[j3];
        float v0 = in[(size_t)j0 * 64 + lane];
        float v1 = in[(size_t)j1 * 64 + lane];
        float v2 = in[(size_t)j2 * 64 + lane];
        float v3 = in[(size_t)j3 * 64 + lane];
        acc += di * (w0 * v0 + w1 * v1 + w2 * v2 + w3 * v3);
    }
    for (; e < c; e++) {
        int j = csr[s + e];
        acc += di * dinv[j] * in[(size_t)j * 64 + lane];
    }
    if (BIAS) acc += bias[lane];
    if (RELU) acc = fmaxf(acc, 0.f);
    out[(size_t)gw * 64 + lane] = acc;
}

// ---------------- fused GEMM2 (+bias,relu) + GEMM3: t = relu(a2@W2+b2) @ W3 ----------------
// Each wave covers all 256 cols (lane -> 4 cols) for 16 nodes; h2 stays in registers.
__global__ __launch_bounds__(256, 2) void gemm23_kernel(const float* __restrict__ a2,
                                                        const float* __restrict__ W2,
                                                        const float* __restrict__ b2,
                                                        const float* __restrict__ W3,
                                                        float* __restrict__ t, int N) {
    __shared__ float w2s[64 * 256];
    __shared__ float b2s[256];
    __shared__ float w3s[256];
    const int tid = threadIdx.x;
#pragma unroll
    for (int i = 0; i < 16; i++) {
        int f4 = tid + i * 256;
        *(float4*)&w2s[f4 * 4] = *(const float4*)&W2[f4 * 4];
    }
    b2s[tid] = b2[tid];
    w3s[tid] = W3[tid];
    __syncthreads();

    const int lane = tid & 63;
    const int wave = tid >> 6;
    const int nodeBase = blockIdx.x * 64 + wave * 16;

    float4 w3f = *(const float4*)&w3s[lane * 4];
    float4 b2f = *(const float4*)&b2s[lane * 4];

    float acc[16][4];
#pragma unroll
    for (int n = 0; n < 16; n++) {
        acc[n][0] = 0.f; acc[n][1] = 0.f; acc[n][2] = 0.f; acc[n][3] = 0.f;
    }

    for (int k4 = 0; k4 < 64; k4 += 4) {
        float4 wf0 = *(const float4*)&w2s[(k4 + 0) * 256 + lane * 4];
        float4 wf1 = *(const float4*)&w2s[(k4 + 1) * 256 + lane * 4];
        float4 wf2 = *(const float4*)&w2s[(k4 + 2) * 256 + lane * 4];
        float4 wf3 = *(const float4*)&w2s[(k4 + 3) * 256 + lane * 4];
#pragma unroll
        for (int n = 0; n < 16; n++) {
            int gn = nodeBase + n;
            if (gn >= N) gn = N - 1;
            float4 av = *(const float4*)&a2[(size_t)gn * 64 + k4];
            acc[n][0] = fmaf(av.x, wf0.x, acc[n][0]);
            acc[n][1] = fmaf(av.x, wf0.y, acc[n][1]);
            acc[n][2] = fmaf(av.x, wf0.z, acc[n][2]);
            acc[n][3] = fmaf(av.x, wf0.w, acc[n][3]);
            acc[n][0] = fmaf(av.y, wf1.x, acc[n][0]);
            acc[n][1] = fmaf(av.y, wf1.y, acc[n][1]);
            acc[n][2] = fmaf(av.y, wf1.z, acc[n][2]);
            acc[n][3] = fmaf(av.y, wf1.w, acc[n][3]);
            acc[n][0] = fmaf(av.z, wf2.x, acc[n][0]);
            acc[n][1] = fmaf(av.z, wf2.y, acc[n][1]);
            acc[n][2] = fmaf(av.z, wf2.z, acc[n][2]);
            acc[n][3] = fmaf(av.z, wf2.w, acc[n][3]);
            acc[n][0] = fmaf(av.w, wf3.x, acc[n][0]);
            acc[n][1] = fmaf(av.w, wf3.y, acc[n][1]);
            acc[n][2] = fmaf(av.w, wf3.z, acc[n][2]);
            acc[n][3] = fmaf(av.w, wf3.w, acc[n][3]);
        }
    }

#pragma unroll
    for (int n = 0; n < 16; n++) {
        float r0 = fmaxf(acc[n][0] + b2f.x, 0.f);
        float r1 = fmaxf(acc[n][1] + b2f.y, 0.f);
        float r2 = fmaxf(acc[n][2] + b2f.z, 0.f);
        float r3 = fmaxf(acc[n][3] + b2f.w, 0.f);
        float p = r0 * w3f.x + r1 * w3f.y + r2 * w3f.z + r3 * w3f.w;
#pragma unroll
        for (int off = 32; off > 0; off >>= 1) p += __shfl_down(p, off, 64);
        int gn = nodeBase + n;
        if (lane == 0 && gn < N) t[gn] = p;
    }
}

// ---------------- scalar aggregation of t + BCE loss + mean reduce ----------------
__global__ void loss_kernel(const float* __restrict__ t, const float* __restrict__ dinv,
                            const int* __restrict__ row_start, const int* __restrict__ cnt,
                            const int* __restrict__ csr, const float* __restrict__ y,
                            const float* __restrict__ b3, float* __restrict__ out,
                            int N, float invN) {
    int i = blockIdx.x * blockDim.x + threadIdx.x;
    float loss = 0.f;
    if (i < N) {
        float di = dinv[i];
        float aedge = 0.f;
        int s = row_start[i], c = cnt[i];
        int e = 0;
        for (; e + 4 <= c; e += 4) {
            int j0 = csr[s + e + 0], j1 = csr[s + e + 1];
            int j2 = csr[s + e + 2], j3 = csr[s + e + 3];
            aedge += dinv[j0] * t[j0] + dinv[j1] * t[j1] + dinv[j2] * t[j2] + dinv[j3] * t[j3];
        }
        for (; e < c; e++) { int j = csr[s + e]; aedge += dinv[j] * t[j]; }
        float z = di * (di * t[i] + aedge) + b3[0];
        float yv = y[i];
        float L = log1pf(expf(-fabsf(z)));
        float spz  = fmaxf(z, 0.f) + L;    // softplus(z)
        float spnz = fmaxf(-z, 0.f) + L;   // softplus(-z)
        loss = yv * spnz + (1.f - yv) * spz;
    }
#pragma unroll
    for (int off = 32; off > 0; off >>= 1) loss += __shfl_down(loss, off, 64);
    __shared__ float red[4];
    int lane = threadIdx.x & 63, wave = threadIdx.x >> 6;
    if (lane == 0) red[wave] = loss;
    __syncthreads();
    if (threadIdx.x == 0)
        atomicAdd(out, (red[0] + red[1] + red[2] + red[3]) * invN);
}

// ---------------- launch ----------------
extern "C" void kernel_launch(void* const* d_in, const int* in_sizes, int n_in,
                              void* d_out, int out_size, void* d_ws, size_t ws_size,
                              hipStream_t stream) {
    const float* x  = (const float*)d_in[0];
    const int*   ei = (const int*)d_in[1];
    const float* y  = (const float*)d_in[2];
    const float* W1 = (const float*)d_in[3];
    const float* b1 = (const float*)d_in[4];
    const float* W2 = (const float*)d_in[5];
    const float* b2 = (const float*)d_in[6];
    const float* W3 = (const float*)d_in[7];
    const float* b3 = (const float*)d_in[8];

    const int N = in_sizes[2];        // y has N elements
    const int E = in_sizes[1] / 2;
    const int* src  = ei;
    const int* dstp = ei + E;

    char* w = (char*)d_ws;
    int*   cnt       = (int*)w;   w += (size_t)N * 4;
    int*   cursor    = (int*)w;   w += (size_t)N * 4;
    int*   total     = (int*)w;   w += 16;
    int*   row_start = (int*)w;   w += (size_t)N * 4;
    float* dinv      = (float*)w; w += (size_t)N * 4;
    int*   csr       = (int*)w;   w += (size_t)E * 4;
    float* bufA      = (float*)w; w += (size_t)N * 64 * 4;   // xw1, later a2
    float* bufB      = (float*)w; w += (size_t)N * 64 * 4;   // h1, later t

    // zero cnt + cursor + total in one shot; zero the output scalar
    hipMemsetAsync(cnt, 0, (size_t)N * 8 + 16, stream);
    hipMemsetAsync(d_out, 0, sizeof(float), stream);

    const int tb = 256;
    hist_kernel<<<(E + tb - 1) / tb, tb, 0, stream>>>(dstp, E, cnt);
    alloc_kernel<<<(N + tb - 1) / tb, tb, 0, stream>>>(cnt, row_start, dinv, total, N);
    scatter_kernel<<<(E + tb - 1) / tb, tb, 0, stream>>>(src, dstp, E, row_start, cursor, csr);

    // layer 1: xw1 = x @ W1 ; h1 = relu(agg(xw1) + b1)
    gemm1_kernel<<<(N + 255) / 256, 256, 0, stream>>>(x, W1, bufA, N);
    agg64_kernel<1, 1><<<(N + 3) / 4, 256, 0, stream>>>(bufA, bufB, row_start, cnt, csr, dinv, b1, N);

    // layer 2 pre-agg: a2 = agg(h1)   (aggregate BEFORE the 64->256 matmul)
    agg64_kernel<0, 0><<<(N + 3) / 4, 256, 0, stream>>>(bufB, bufA, row_start, cnt, csr, dinv, nullptr, N);

    // layers 2+3 fused: t = relu(a2 @ W2 + b2) @ W3   (h2 never hits memory)
    gemm23_kernel<<<(N + 63) / 64, 256, 0, stream>>>(bufA, W2, b2, W3, bufB, N);

    // layer 3 aggregation (scalar) + BCE + mean
    loss_kernel<<<(N + tb - 1) / tb, tb, 0, stream>>>(bufB, dinv, row_start, cnt, csr, y, b3,
                                                      (float*)d_out, N, 1.0f / N);
}

// Round 2
// 779.049 us; speedup vs baseline: 1.2329x; 1.2329x over previous
//
#include <hip/hip_runtime.h>
#include <math.h>

// ---------------- CSR build ----------------

__global__ void hist_kernel(const int* __restrict__ dst, int E, int* __restrict__ cnt) {
    int e = blockIdx.x * blockDim.x + threadIdx.x;
    if (e < E) atomicAdd(&cnt[dst[e]], 1);
}

// wave-scan segment allocation + dinv = rsqrt(deg+1)
__global__ void alloc_kernel(const int* __restrict__ cnt, int* __restrict__ row_start,
                             float* __restrict__ dinv, int* __restrict__ total, int N) {
    int i = blockIdx.x * blockDim.x + threadIdx.x;
    int lane = threadIdx.x & 63;
    int c = (i < N) ? cnt[i] : 0;
    int inc = c;
#pragma unroll
    for (int o = 1; o < 64; o <<= 1) {
        int v = __shfl_up(inc, o, 64);
        if (lane >= o) inc += v;
    }
    int wsum = __shfl(inc, 63, 64);
    int base = 0;
    if (lane == 0) base = atomicAdd(total, wsum);
    base = __shfl(base, 0, 64);
    if (i < N) {
        row_start[i] = base + inc - c;
        dinv[i] = rsqrtf((float)(c + 1));
    }
}

__global__ void scatter_kernel(const int* __restrict__ src, const int* __restrict__ dst, int E,
                               const int* __restrict__ row_start, int* __restrict__ cursor,
                               int* __restrict__ csr) {
    int e = blockIdx.x * blockDim.x + threadIdx.x;
    if (e < E) {
        int d = dst[e];
        int p = row_start[d] + atomicAdd(&cursor[d], 1);
        csr[p] = src[e];
    }
}

// ---------------- GEMM1: xw1 = x @ W1   (N x 512) @ (512 x 64) ----------------
// Register-tiled: block = 256 thr, tile = 128 nodes x 64 cols, thread = 4 nodes x 8 cols.
// x tile staged as [k4][node][4k] float4 (aligned b128, conflict-free, coalesced loads).
// Inner loop per k4: 4 b128 x (8-way broadcast) + 8 b128 W (8-way broadcast) + 128 FMA.
#define G1_KC 64
__global__ __launch_bounds__(256, 3) void gemm1_kernel(const float* __restrict__ x,
                                                       const float* __restrict__ W,
                                                       float* __restrict__ out, int N) {
    __shared__ float xs[(G1_KC / 4) * 128 * 4];   // 32 KB: [k4][node][4]
    __shared__ float ws[G1_KC * 64];              // 16 KB: [k][col]
    const int tid = threadIdx.x;
    const int nodeBase = blockIdx.x * 128;
    const int cg = tid & 7;     // cols cg*8 .. cg*8+7
    const int ng = tid >> 3;    // nodes ng*4 .. ng*4+3

    float acc[4][8];
#pragma unroll
    for (int n = 0; n < 4; n++)
#pragma unroll
        for (int c = 0; c < 8; c++) acc[n][c] = 0.f;

    for (int kc = 0; kc < 512; kc += G1_KC) {
        __syncthreads();
        // stage x tile: 128 nodes x 64 k = 2048 float4, 8 per thread; coalesced
#pragma unroll
        for (int i = 0; i < 8; i++) {
            int f4 = tid + i * 256;        // 0..2047
            int node = f4 >> 4;            // 0..127
            int kp = (f4 & 15) << 2;       // 0,4,..,60
            int gn = nodeBase + node;
            if (gn >= N) gn = N - 1;
            float4 v = *(const float4*)(x + (size_t)gn * 512 + kc + kp);
            *(float4*)&xs[(kp >> 2) * 512 + node * 4] = v;
        }
        // stage W chunk: 64 k x 64 cols = 1024 float4, 4 per thread
#pragma unroll
        for (int i = 0; i < 4; i++) {
            int f4 = tid + i * 256;        // 0..1023
            int k = f4 >> 4;               // 0..63
            int cp = (f4 & 15) << 2;
            *(float4*)&ws[k * 64 + cp] = *(const float4*)(W + (size_t)(kc + k) * 64 + cp);
        }
        __syncthreads();
#pragma unroll 4
        for (int k4 = 0; k4 < G1_KC / 4; k4++) {
            float4 xv[4];
#pragma unroll
            for (int n = 0; n < 4; n++)
                xv[n] = *(const float4*)&xs[k4 * 512 + (ng * 4 + n) * 4];
            float4 wv[4][2];
#pragma unroll
            for (int kk = 0; kk < 4; kk++) {
                wv[kk][0] = *(const float4*)&ws[(k4 * 4 + kk) * 64 + cg * 8];
                wv[kk][1] = *(const float4*)&ws[(k4 * 4 + kk) * 64 + cg * 8 + 4];
            }
#pragma unroll
            for (int n = 0; n < 4; n++) {
                float xk0 = xv[n].x, xk1 = xv[n].y, xk2 = xv[n].z, xk3 = xv[n].w;
#pragma unroll
                for (int kk = 0; kk < 4; kk++) {
                    float xk = (kk == 0) ? xk0 : (kk == 1) ? xk1 : (kk == 2) ? xk2 : xk3;
                    acc[n][0] = fmaf(xk, wv[kk][0].x, acc[n][0]);
                    acc[n][1] = fmaf(xk, wv[kk][0].y, acc[n][1]);
                    acc[n][2] = fmaf(xk, wv[kk][0].z, acc[n][2]);
                    acc[n][3] = fmaf(xk, wv[kk][0].w, acc[n][3]);
                    acc[n][4] = fmaf(xk, wv[kk][1].x, acc[n][4]);
                    acc[n][5] = fmaf(xk, wv[kk][1].y, acc[n][5]);
                    acc[n][6] = fmaf(xk, wv[kk][1].z, acc[n][6]);
                    acc[n][7] = fmaf(xk, wv[kk][1].w, acc[n][7]);
                }
            }
        }
    }
    const int myNode = nodeBase + ng * 4;
#pragma unroll
    for (int n = 0; n < 4; n++) {
        int gn = myNode + n;
        if (gn < N) {
            *(float4*)(out + (size_t)gn * 64 + cg * 8) =
                make_float4(acc[n][0], acc[n][1], acc[n][2], acc[n][3]);
            *(float4*)(out + (size_t)gn * 64 + cg * 8 + 4) =
                make_float4(acc[n][4], acc[n][5], acc[n][6], acc[n][7]);
        }
    }
}

// ---------------- 64-dim CSR aggregation (one wave per node, lane = feature) ----------------
template <int RELU, int BIAS>
__global__ void agg64_kernel(const float* __restrict__ in, float* __restrict__ out,
                             const int* __restrict__ row_start, const int* __restrict__ cnt,
                             const int* __restrict__ csr, const float* __restrict__ dinv,
                             const float* __restrict__ bias, int N) {
    int gw = (int)((blockIdx.x * (size_t)blockDim.x + threadIdx.x) >> 6);
    int lane = threadIdx.x & 63;
    if (gw >= N) return;
    float di = dinv[gw];
    float acc = di * di * in[(size_t)gw * 64 + lane];   // self loop
    int s = row_start[gw];
    int c = cnt[gw];
    int e = 0;
    for (; e + 4 <= c; e += 4) {   // 4 gathers in flight for latency hiding
        int j0 = csr[s + e + 0], j1 = csr[s + e + 1], j2 = csr[s + e + 2], j3 = csr[s + e + 3];
        float w0 = dinv[j0], w1 = dinv[j1], w2 = dinv[j2], w3 = dinv[j3];
        float v0 = in[(size_t)j0 * 64 + lane];
        float v1 = in[(size_t)j1 * 64 + lane];
        float v2 = in[(size_t)j2 * 64 + lane];
        float v3 = in[(size_t)j3 * 64 + lane];
        acc += di * (w0 * v0 + w1 * v1 + w2 * v2 + w3 * v3);
    }
    for (; e < c; e++) {
        int j = csr[s + e];
        acc += di * dinv[j] * in[(size_t)j * 64 + lane];
    }
    if (BIAS) acc += bias[lane];
    if (RELU) acc = fmaxf(acc, 0.f);
    out[(size_t)gw * 64 + lane] = acc;
}

// ---------------- fused GEMM2 (+bias,relu) + GEMM3: t = relu(a2@W2+b2) @ W3 ----------------
__global__ __launch_bounds__(256, 2) void gemm23_kernel(const float* __restrict__ a2,
                                                        const float* __restrict__ W2,
                                                        const float* __restrict__ b2,
                                                        const float* __restrict__ W3,
                                                        float* __restrict__ t, int N) {
    __shared__ float w2s[64 * 256];
    __shared__ float b2s[256];
    __shared__ float w3s[256];
    const int tid = threadIdx.x;
#pragma unroll
    for (int i = 0; i < 16; i++) {
        int f4 = tid + i * 256;
        *(float4*)&w2s[f4 * 4] = *(const float4*)&W2[f4 * 4];
    }
    b2s[tid] = b2[tid];
    w3s[tid] = W3[tid];
    __syncthreads();

    const int lane = tid & 63;
    const int wave = tid >> 6;
    const int nodeBase = blockIdx.x * 64 + wave * 16;

    float4 w3f = *(const float4*)&w3s[lane * 4];
    float4 b2f = *(const float4*)&b2s[lane * 4];

    float acc[16][4];
#pragma unroll
    for (int n = 0; n < 16; n++) {
        acc[n][0] = 0.f; acc[n][1] = 0.f; acc[n][2] = 0.f; acc[n][3] = 0.f;
    }

    for (int k4 = 0; k4 < 64; k4 += 4) {
        float4 wf0 = *(const float4*)&w2s[(k4 + 0) * 256 + lane * 4];
        float4 wf1 = *(const float4*)&w2s[(k4 + 1) * 256 + lane * 4];
        float4 wf2 = *(const float4*)&w2s[(k4 + 2) * 256 + lane * 4];
        float4 wf3 = *(const float4*)&w2s[(k4 + 3) * 256 + lane * 4];
#pragma unroll
        for (int n = 0; n < 16; n++) {
            int gn = nodeBase + n;
            if (gn >= N) gn = N - 1;
            float4 av = *(const float4*)&a2[(size_t)gn * 64 + k4];
            acc[n][0] = fmaf(av.x, wf0.x, acc[n][0]);
            acc[n][1] = fmaf(av.x, wf0.y, acc[n][1]);
            acc[n][2] = fmaf(av.x, wf0.z, acc[n][2]);
            acc[n][3] = fmaf(av.x, wf0.w, acc[n][3]);
            acc[n][0] = fmaf(av.y, wf1.x, acc[n][0]);
            acc[n][1] = fmaf(av.y, wf1.y, acc[n][1]);
            acc[n][2] = fmaf(av.y, wf1.z, acc[n][2]);
            acc[n][3] = fmaf(av.y, wf1.w, acc[n][3]);
            acc[n][0] = fmaf(av.z, wf2.x, acc[n][0]);
            acc[n][1] = fmaf(av.z, wf2.y, acc[n][1]);
            acc[n][2] = fmaf(av.z, wf2.z, acc[n][2]);
            acc[n][3] = fmaf(av.z, wf2.w, acc[n][3]);
            acc[n][0] = fmaf(av.w, wf3.x, acc[n][0]);
            acc[n][1] = fmaf(av.w, wf3.y, acc[n][1]);
            acc[n][2] = fmaf(av.w, wf3.z, acc[n][2]);
            acc[n][3] = fmaf(av.w, wf3.w, acc[n][3]);
        }
    }

#pragma unroll
    for (int n = 0; n < 16; n++) {
        float r0 = fmaxf(acc[n][0] + b2f.x, 0.f);
        float r1 = fmaxf(acc[n][1] + b2f.y, 0.f);
        float r2 = fmaxf(acc[n][2] + b2f.z, 0.f);
        float r3 = fmaxf(acc[n][3] + b2f.w, 0.f);
        float p = r0 * w3f.x + r1 * w3f.y + r2 * w3f.z + r3 * w3f.w;
#pragma unroll
        for (int off = 32; off > 0; off >>= 1) p += __shfl_down(p, off, 64);
        int gn = nodeBase + n;
        if (lane == 0 && gn < N) t[gn] = p;
    }
}

// ---------------- scalar aggregation of t + BCE loss + mean reduce ----------------
__global__ void loss_kernel(const float* __restrict__ t, const float* __restrict__ dinv,
                            const int* __restrict__ row_start, const int* __restrict__ cnt,
                            const int* __restrict__ csr, const float* __restrict__ y,
                            const float* __restrict__ b3, float* __restrict__ out,
                            int N, float invN) {
    int i = blockIdx.x * blockDim.x + threadIdx.x;
    float loss = 0.f;
    if (i < N) {
        float di = dinv[i];
        float aedge = 0.f;
        int s = row_start[i], c = cnt[i];
        int e = 0;
        for (; e + 4 <= c; e += 4) {
            int j0 = csr[s + e + 0], j1 = csr[s + e + 1];
            int j2 = csr[s + e + 2], j3 = csr[s + e + 3];
            aedge += dinv[j0] * t[j0] + dinv[j1] * t[j1] + dinv[j2] * t[j2] + dinv[j3] * t[j3];
        }
        for (; e < c; e++) { int j = csr[s + e]; aedge += dinv[j] * t[j]; }
        float z = di * (di * t[i] + aedge) + b3[0];
        float yv = y[i];
        float L = log1pf(expf(-fabsf(z)));
        float spz  = fmaxf(z, 0.f) + L;    // softplus(z)
        float spnz = fmaxf(-z, 0.f) + L;   // softplus(-z)
        loss = yv * spnz + (1.f - yv) * spz;
    }
#pragma unroll
    for (int off = 32; off > 0; off >>= 1) loss += __shfl_down(loss, off, 64);
    __shared__ float red[4];
    int lane = threadIdx.x & 63, wave = threadIdx.x >> 6;
    if (lane == 0) red[wave] = loss;
    __syncthreads();
    if (threadIdx.x == 0)
        atomicAdd(out, (red[0] + red[1] + red[2] + red[3]) * invN);
}

// ---------------- launch ----------------
extern "C" void kernel_launch(void* const* d_in, const int* in_sizes, int n_in,
                              void* d_out, int out_size, void* d_ws, size_t ws_size,
                              hipStream_t stream) {
    const float* x  = (const float*)d_in[0];
    const int*   ei = (const int*)d_in[1];
    const float* y  = (const float*)d_in[2];
    const float* W1 = (const float*)d_in[3];
    const float* b1 = (const float*)d_in[4];
    const float* W2 = (const float*)d_in[5];
    const float* b2 = (const float*)d_in[6];
    const float* W3 = (const float*)d_in[7];
    const float* b3 = (const float*)d_in[8];

    const int N = in_sizes[2];        // y has N elements
    const int E = in_sizes[1] / 2;
    const int* src  = ei;
    const int* dstp = ei + E;

    char* w = (char*)d_ws;
    int*   cnt       = (int*)w;   w += (size_t)N * 4;
    int*   cursor    = (int*)w;   w += (size_t)N * 4;
    int*   total     = (int*)w;   w += 16;
    int*   row_start = (int*)w;   w += (size_t)N * 4;
    float* dinv      = (float*)w; w += (size_t)N * 4;
    int*   csr       = (int*)w;   w += (size_t)E * 4;
    float* bufA      = (float*)w; w += (size_t)N * 64 * 4;   // xw1, later a2
    float* bufB      = (float*)w; w += (size_t)N * 64 * 4;   // h1, later t

    hipMemsetAsync(cnt, 0, (size_t)N * 8 + 16, stream);
    hipMemsetAsync(d_out, 0, sizeof(float), stream);

    const int tb = 256;
    hist_kernel<<<(E + tb - 1) / tb, tb, 0, stream>>>(dstp, E, cnt);
    alloc_kernel<<<(N + tb - 1) / tb, tb, 0, stream>>>(cnt, row_start, dinv, total, N);
    scatter_kernel<<<(E + tb - 1) / tb, tb, 0, stream>>>(src, dstp, E, row_start, cursor, csr);

    // layer 1: xw1 = x @ W1 ; h1 = relu(agg(xw1) + b1)
    gemm1_kernel<<<(N + 127) / 128, 256, 0, stream>>>(x, W1, bufA, N);
    agg64_kernel<1, 1><<<(N + 3) / 4, 256, 0, stream>>>(bufA, bufB, row_start, cnt, csr, dinv, b1, N);

    // layer 2 pre-agg: a2 = agg(h1)   (aggregate BEFORE the 64->256 matmul)
    agg64_kernel<0, 0><<<(N + 3) / 4, 256, 0, stream>>>(bufB, bufA, row_start, cnt, csr, dinv, nullptr, N);

    // layers 2+3 fused: t = relu(a2 @ W2 + b2) @ W3   (h2 never hits memory)
    gemm23_kernel<<<(N + 63) / 64, 256, 0, stream>>>(bufA, W2, b2, W3, bufB, N);

    // layer 3 aggregation (scalar) + BCE + mean
    loss_kernel<<<(N + tb - 1) / tb, tb, 0, stream>>>(bufB, dinv, row_start, cnt, csr, y, b3,
                                                      (float*)d_out, N, 1.0f / N);
}

// Round 3
// 749.200 us; speedup vs baseline: 1.2820x; 1.0398x over previous
//
#include <hip/hip_runtime.h>
#include <math.h>

typedef __attribute__((ext_vector_type(8))) short s16x8;   // 8 bf16 (4 VGPRs)
typedef __attribute__((ext_vector_type(4))) float f32x4;

__device__ inline ushort f2bf(float f) {
    union { float f; unsigned u; } v; v.f = f;
    unsigned r = v.u + 0x7FFF + ((v.u >> 16) & 1);   // RTN-even
    return (ushort)(r >> 16);
}
__device__ inline float bf2f(ushort h) {
    union { unsigned u; float f; } v; v.u = ((unsigned)h) << 16;
    return v.f;
}

// ---------------- CSR build ----------------

__global__ void hist_kernel(const int* __restrict__ dst, int E, int* __restrict__ cnt) {
    int e = blockIdx.x * blockDim.x + threadIdx.x;
    if (e < E) atomicAdd(&cnt[dst[e]], 1);
}

__global__ void alloc_kernel(const int* __restrict__ cnt, int* __restrict__ row_start,
                             float* __restrict__ dinv, int* __restrict__ total, int N) {
    int i = blockIdx.x * blockDim.x + threadIdx.x;
    int lane = threadIdx.x & 63;
    int c = (i < N) ? cnt[i] : 0;
    int inc = c;
#pragma unroll
    for (int o = 1; o < 64; o <<= 1) {
        int v = __shfl_up(inc, o, 64);
        if (lane >= o) inc += v;
    }
    int wsum = __shfl(inc, 63, 64);
    int base = 0;
    if (lane == 0) base = atomicAdd(total, wsum);
    base = __shfl(base, 0, 64);
    if (i < N) {
        row_start[i] = base + inc - c;
        dinv[i] = rsqrtf((float)(c + 1));
    }
}

__global__ void scatter_kernel(const int* __restrict__ src, const int* __restrict__ dst, int E,
                               const int* __restrict__ row_start, int* __restrict__ cursor,
                               int* __restrict__ csr) {
    int e = blockIdx.x * blockDim.x + threadIdx.x;
    if (e < E) {
        int d = dst[e];
        int p = row_start[d] + atomicAdd(&cursor[d], 1);
        csr[p] = src[e];
    }
}

// ---------------- W1^T hi/lo split precompute: wt[n][k] bf16 ----------------
__global__ void wsplit_kernel(const float* __restrict__ W, ushort* __restrict__ wt_hi,
                              ushort* __restrict__ wt_lo) {
    int idx = blockIdx.x * blockDim.x + threadIdx.x;
    if (idx < 64 * 512) {
        int n = idx & 63, k = idx >> 6;           // read coalesced over n
        float f = W[k * 64 + n];
        ushort h = f2bf(f);
        wt_hi[n * 512 + k] = h;
        wt_lo[n * 512 + k] = f2bf(f - bf2f(h));
    }
}

// ---------------- GEMM1 (MFMA): xw1 = x @ W1, bf16 hi/lo 3-term split ----------------
// block = 256 thr (4 waves), tile = 128 nodes x 64 cols, K-chunk = 64.
// LDS 48 KB -> 3 blocks/CU. XOR group-swizzle (g^=row) keeps b128 reads 2-way max.
// Per wave per chunk: 24 ds_read_b128 + 48 MFMA; memory-streaming-bound overall.
__global__ __launch_bounds__(256, 3) void gemm1_kernel(const float* __restrict__ x,
                                                       const ushort* __restrict__ wt_hi,
                                                       const ushort* __restrict__ wt_lo,
                                                       float* __restrict__ out, int N) {
    __shared__ __align__(16) short xs_hi[128 * 64];   // 16 KB  [node][g'*8+j]
    __shared__ __align__(16) short xs_lo[128 * 64];   // 16 KB
    __shared__ __align__(16) short ws_hi[64 * 64];    //  8 KB  [n][g'*8+j]
    __shared__ __align__(16) short ws_lo[64 * 64];    //  8 KB

    const int tid = threadIdx.x;
    const int nodeBase = blockIdx.x * 128;
    const int wave = tid >> 6, lane = tid & 63;
    const int m16 = lane & 15, quad = lane >> 4;

    f32x4 acc[2][4];
#pragma unroll
    for (int mt = 0; mt < 2; mt++)
#pragma unroll
        for (int nt = 0; nt < 4; nt++) acc[mt][nt] = (f32x4){0.f, 0.f, 0.f, 0.f};

    for (int kc = 0; kc < 512; kc += 64) {
        __syncthreads();
        // stage x tile: 128 nodes x 8 groups(16B); coalesced 32B/thread/iter
#pragma unroll
        for (int i = 0; i < 4; i++) {
            int f = tid + i * 256;            // 0..1023
            int node = f >> 3, g = f & 7;
            int gn = nodeBase + node;
            if (gn >= N) gn = N - 1;
            const float4 a = *(const float4*)(x + (size_t)gn * 512 + kc + g * 8);
            const float4 b = *(const float4*)(x + (size_t)gn * 512 + kc + g * 8 + 4);
            float ff[8] = {a.x, a.y, a.z, a.w, b.x, b.y, b.z, b.w};
            union { ushort u[8]; uint4 v; } H, L;
#pragma unroll
            for (int j = 0; j < 8; j++) {
                ushort h = f2bf(ff[j]);
                H.u[j] = h;
                L.u[j] = f2bf(ff[j] - bf2f(h));
            }
            int gp = (g + node) & 7;
            *(uint4*)&xs_hi[node * 64 + gp * 8] = H.v;
            *(uint4*)&xs_lo[node * 64 + gp * 8] = L.v;
        }
        // stage W^T chunk: 64 n x 8 groups, already bf16
#pragma unroll
        for (int i = 0; i < 2; i++) {
            int f = tid + i * 256;            // 0..511
            int n = f >> 3, g = f & 7;
            int gp = (g + n) & 7;
            *(uint4*)&ws_hi[n * 64 + gp * 8] =
                *(const uint4*)(wt_hi + (size_t)n * 512 + kc + g * 8);
            *(uint4*)&ws_lo[n * 64 + gp * 8] =
                *(const uint4*)(wt_lo + (size_t)n * 512 + kc + g * 8);
        }
        __syncthreads();
#pragma unroll
        for (int ck = 0; ck < 2; ck++) {
            s16x8 Ah[2], Al[2];
#pragma unroll
            for (int mt = 0; mt < 2; mt++) {
                int row = (wave * 2 + mt) * 16 + m16;     // local 0..127
                int gp = (ck * 4 + quad + row) & 7;
                Ah[mt] = *(s16x8*)&xs_hi[row * 64 + gp * 8];
                Al[mt] = *(s16x8*)&xs_lo[row * 64 + gp * 8];
            }
#pragma unroll
            for (int nt = 0; nt < 4; nt++) {
                int n = nt * 16 + m16;                    // local 0..63
                int gp = (ck * 4 + quad + n) & 7;
                s16x8 Bh = *(s16x8*)&ws_hi[n * 64 + gp * 8];
                s16x8 Bl = *(s16x8*)&ws_lo[n * 64 + gp * 8];
#pragma unroll
                for (int mt = 0; mt < 2; mt++) {
                    acc[mt][nt] = __builtin_amdgcn_mfma_f32_16x16x32_bf16(Ah[mt], Bh, acc[mt][nt], 0, 0, 0);
                    acc[mt][nt] = __builtin_amdgcn_mfma_f32_16x16x32_bf16(Ah[mt], Bl, acc[mt][nt], 0, 0, 0);
                    acc[mt][nt] = __builtin_amdgcn_mfma_f32_16x16x32_bf16(Al[mt], Bh, acc[mt][nt], 0, 0, 0);
                }
            }
        }
    }
    // C/D layout: col = lane&15, row = quad*4 + reg
#pragma unroll
    for (int mt = 0; mt < 2; mt++) {
#pragma unroll
        for (int r = 0; r < 4; r++) {
            int gn = nodeBase + (wave * 2 + mt) * 16 + quad * 4 + r;
            if (gn < N) {
#pragma unroll
                for (int nt = 0; nt < 4; nt++)
                    out[(size_t)gn * 64 + nt * 16 + m16] = acc[mt][nt][r];
            }
        }
    }
}

// ---------------- 64-dim CSR aggregation (one wave per node, lane = feature) ----------------
template <int RELU, int BIAS>
__global__ void agg64_kernel(const float* __restrict__ in, float* __restrict__ out,
                             const int* __restrict__ row_start, const int* __restrict__ cnt,
                             const int* __restrict__ csr, const float* __restrict__ dinv,
                             const float* __restrict__ bias, int N) {
    int gw = (int)((blockIdx.x * (size_t)blockDim.x + threadIdx.x) >> 6);
    int lane = threadIdx.x & 63;
    if (gw >= N) return;
    float di = dinv[gw];
    float acc = di * di * in[(size_t)gw * 64 + lane];   // self loop
    int s = row_start[gw];
    int c = cnt[gw];
    int e = 0;
    for (; e + 8 <= c; e += 8) {   // 8 gathers in flight for latency hiding
        int j0 = csr[s + e + 0], j1 = csr[s + e + 1], j2 = csr[s + e + 2], j3 = csr[s + e + 3];
        int j4 = csr[s + e + 4], j5 = csr[s + e + 5], j6 = csr[s + e + 6], j7 = csr[s + e + 7];
        float v0 = in[(size_t)j0 * 64 + lane];
        float v1 = in[(size_t)j1 * 64 + lane];
        float v2 = in[(size_t)j2 * 64 + lane];
        float v3 = in[(size_t)j3 * 64 + lane];
        float v4 = in[(size_t)j4 * 64 + lane];
        float v5 = in[(size_t)j5 * 64 + lane];
        float v6 = in[(size_t)j6 * 64 + lane];
        float v7 = in[(size_t)j7 * 64 + lane];
        float s0 = dinv[j0] * v0 + dinv[j1] * v1 + dinv[j2] * v2 + dinv[j3] * v3;
        float s1 = dinv[j4] * v4 + dinv[j5] * v5 + dinv[j6] * v6 + dinv[j7] * v7;
        acc += di * (s0 + s1);
    }
    for (; e < c; e++) {
        int j = csr[s + e];
        acc += di * dinv[j] * in[(size_t)j * 64 + lane];
    }
    if (BIAS) acc += bias[lane];
    if (RELU) acc = fmaxf(acc, 0.f);
    out[(size_t)gw * 64 + lane] = acc;
}

// ---------------- fused GEMM2 (+bias,relu) + GEMM3: t = relu(a2@W2+b2) @ W3 ----------------
__global__ __launch_bounds__(256, 2) void gemm23_kernel(const float* __restrict__ a2,
                                                        const float* __restrict__ W2,
                                                        const float* __restrict__ b2,
                                                        const float* __restrict__ W3,
                                                        float* __restrict__ t, int N) {
    __shared__ float w2s[64 * 256];
    __shared__ float b2s[256];
    __shared__ float w3s[256];
    const int tid = threadIdx.x;
#pragma unroll
    for (int i = 0; i < 16; i++) {
        int f4 = tid + i * 256;
        *(float4*)&w2s[f4 * 4] = *(const float4*)&W2[f4 * 4];
    }
    b2s[tid] = b2[tid];
    w3s[tid] = W3[tid];
    __syncthreads();

    const int lane = tid & 63;
    const int wave = tid >> 6;
    const int nodeBase = blockIdx.x * 64 + wave * 16;

    float4 w3f = *(const float4*)&w3s[lane * 4];
    float4 b2f = *(const float4*)&b2s[lane * 4];

    float acc[16][4];
#pragma unroll
    for (int n = 0; n < 16; n++) {
        acc[n][0] = 0.f; acc[n][1] = 0.f; acc[n][2] = 0.f; acc[n][3] = 0.f;
    }

    for (int k4 = 0; k4 < 64; k4 += 4) {
        float4 wf0 = *(const float4*)&w2s[(k4 + 0) * 256 + lane * 4];
        float4 wf1 = *(const float4*)&w2s[(k4 + 1) * 256 + lane * 4];
        float4 wf2 = *(const float4*)&w2s[(k4 + 2) * 256 + lane * 4];
        float4 wf3 = *(const float4*)&w2s[(k4 + 3) * 256 + lane * 4];
#pragma unroll
        for (int n = 0; n < 16; n++) {
            int gn = nodeBase + n;
            if (gn >= N) gn = N - 1;
            float4 av = *(const float4*)&a2[(size_t)gn * 64 + k4];
            acc[n][0] = fmaf(av.x, wf0.x, acc[n][0]);
            acc[n][1] = fmaf(av.x, wf0.y, acc[n][1]);
            acc[n][2] = fmaf(av.x, wf0.z, acc[n][2]);
            acc[n][3] = fmaf(av.x, wf0.w, acc[n][3]);
            acc[n][0] = fmaf(av.y, wf1.x, acc[n][0]);
            acc[n][1] = fmaf(av.y, wf1.y, acc[n][1]);
            acc[n][2] = fmaf(av.y, wf1.z, acc[n][2]);
            acc[n][3] = fmaf(av.y, wf1.w, acc[n][3]);
            acc[n][0] = fmaf(av.z, wf2.x, acc[n][0]);
            acc[n][1] = fmaf(av.z, wf2.y, acc[n][1]);
            acc[n][2] = fmaf(av.z, wf2.z, acc[n][2]);
            acc[n][3] = fmaf(av.z, wf2.w, acc[n][3]);
            acc[n][0] = fmaf(av.w, wf3.x, acc[n][0]);
            acc[n][1] = fmaf(av.w, wf3.y, acc[n][1]);
            acc[n][2] = fmaf(av.w, wf3.z, acc[n][2]);
            acc[n][3] = fmaf(av.w, wf3.w, acc[n][3]);
        }
    }

#pragma unroll
    for (int n = 0; n < 16; n++) {
        float r0 = fmaxf(acc[n][0] + b2f.x, 0.f);
        float r1 = fmaxf(acc[n][1] + b2f.y, 0.f);
        float r2 = fmaxf(acc[n][2] + b2f.z, 0.f);
        float r3 = fmaxf(acc[n][3] + b2f.w, 0.f);
        float p = r0 * w3f.x + r1 * w3f.y + r2 * w3f.z + r3 * w3f.w;
#pragma unroll
        for (int off = 32; off > 0; off >>= 1) p += __shfl_down(p, off, 64);
        int gn = nodeBase + n;
        if (lane == 0 && gn < N) t[gn] = p;
    }
}

// ---------------- scalar aggregation of t + BCE loss + mean reduce ----------------
__global__ void loss_kernel(const float* __restrict__ t, const float* __restrict__ dinv,
                            const int* __restrict__ row_start, const int* __restrict__ cnt,
                            const int* __restrict__ csr, const float* __restrict__ y,
                            const float* __restrict__ b3, float* __restrict__ out,
                            int N, float invN) {
    int i = blockIdx.x * blockDim.x + threadIdx.x;
    float loss = 0.f;
    if (i < N) {
        float di = dinv[i];
        float aedge = 0.f;
        int s = row_start[i], c = cnt[i];
        int e = 0;
        for (; e + 4 <= c; e += 4) {
            int j0 = csr[s + e + 0], j1 = csr[s + e + 1];
            int j2 = csr[s + e + 2], j3 = csr[s + e + 3];
            aedge += dinv[j0] * t[j0] + dinv[j1] * t[j1] + dinv[j2] * t[j2] + dinv[j3] * t[j3];
        }
        for (; e < c; e++) { int j = csr[s + e]; aedge += dinv[j] * t[j]; }
        float z = di * (di * t[i] + aedge) + b3[0];
        float yv = y[i];
        float L = log1pf(expf(-fabsf(z)));
        float spz  = fmaxf(z, 0.f) + L;    // softplus(z)
        float spnz = fmaxf(-z, 0.f) + L;   // softplus(-z)
        loss = yv * spnz + (1.f - yv) * spz;
    }
#pragma unroll
    for (int off = 32; off > 0; off >>= 1) loss += __shfl_down(loss, off, 64);
    __shared__ float red[4];
    int lane = threadIdx.x & 63, wave = threadIdx.x >> 6;
    if (lane == 0) red[wave] = loss;
    __syncthreads();
    if (threadIdx.x == 0)
        atomicAdd(out, (red[0] + red[1] + red[2] + red[3]) * invN);
}

// ---------------- launch ----------------
extern "C" void kernel_launch(void* const* d_in, const int* in_sizes, int n_in,
                              void* d_out, int out_size, void* d_ws, size_t ws_size,
                              hipStream_t stream) {
    const float* x  = (const float*)d_in[0];
    const int*   ei = (const int*)d_in[1];
    const float* y  = (const float*)d_in[2];
    const float* W1 = (const float*)d_in[3];
    const float* b1 = (const float*)d_in[4];
    const float* W2 = (const float*)d_in[5];
    const float* b2 = (const float*)d_in[6];
    const float* W3 = (const float*)d_in[7];
    const float* b3 = (const float*)d_in[8];

    const int N = in_sizes[2];        // y has N elements
    const int E = in_sizes[1] / 2;
    const int* src  = ei;
    const int* dstp = ei + E;

    char* w = (char*)d_ws;
    int*    cnt       = (int*)w;    w += (size_t)N * 4;
    int*    cursor    = (int*)w;    w += (size_t)N * 4;
    int*    total     = (int*)w;    w += 16;
    int*    row_start = (int*)w;    w += (size_t)N * 4;
    float*  dinv      = (float*)w;  w += (size_t)N * 4;
    int*    csr       = (int*)w;    w += (size_t)E * 4;
    ushort* wt_hi     = (ushort*)w; w += (size_t)64 * 512 * 2;
    ushort* wt_lo     = (ushort*)w; w += (size_t)64 * 512 * 2;
    float*  bufA      = (float*)w;  w += (size_t)N * 64 * 4;   // xw1, later a2
    float*  bufB      = (float*)w;  w += (size_t)N * 64 * 4;   // h1, later t

    hipMemsetAsync(cnt, 0, (size_t)N * 8 + 16, stream);
    hipMemsetAsync(d_out, 0, sizeof(float), stream);

    const int tb = 256;
    wsplit_kernel<<<(64 * 512 + tb - 1) / tb, tb, 0, stream>>>(W1, wt_hi, wt_lo);
    hist_kernel<<<(E + tb - 1) / tb, tb, 0, stream>>>(dstp, E, cnt);
    alloc_kernel<<<(N + tb - 1) / tb, tb, 0, stream>>>(cnt, row_start, dinv, total, N);
    scatter_kernel<<<(E + tb - 1) / tb, tb, 0, stream>>>(src, dstp, E, row_start, cursor, csr);

    // layer 1: xw1 = x @ W1 (MFMA, bf16 split) ; h1 = relu(agg(xw1) + b1)
    gemm1_kernel<<<(N + 127) / 128, 256, 0, stream>>>(x, wt_hi, wt_lo, bufA, N);
    agg64_kernel<1, 1><<<(N + 3) / 4, 256, 0, stream>>>(bufA, bufB, row_start, cnt, csr, dinv, b1, N);

    // layer 2 pre-agg: a2 = agg(h1)   (aggregate BEFORE the 64->256 matmul)
    agg64_kernel<0, 0><<<(N + 3) / 4, 256, 0, stream>>>(bufB, bufA, row_start, cnt, csr, dinv, nullptr, N);

    // layers 2+3 fused: t = relu(a2 @ W2 + b2) @ W3   (h2 never hits memory)
    gemm23_kernel<<<(N + 63) / 64, 256, 0, stream>>>(bufA, W2, b2, W3, bufB, N);

    // layer 3 aggregation (scalar) + BCE + mean
    loss_kernel<<<(N + tb - 1) / tb, tb, 0, stream>>>(bufB, dinv, row_start, cnt, csr, y, b3,
                                                      (float*)d_out, N, 1.0f / N);
}

// Round 4
// 732.081 us; speedup vs baseline: 1.3120x; 1.0234x over previous
//
#include <hip/hip_runtime.h>
#include <math.h>

typedef __attribute__((ext_vector_type(8))) short s16x8;   // 8 bf16 (4 VGPRs)
typedef __attribute__((ext_vector_type(4))) float f32x4;

__device__ inline ushort f2bf(float f) {
    union { float f; unsigned u; } v; v.f = f;
    unsigned r = v.u + 0x7FFF + ((v.u >> 16) & 1);   // RTN-even
    return (ushort)(r >> 16);
}
__device__ inline float bf2f(ushort h) {
    union { unsigned u; float f; } v; v.u = ((unsigned)h) << 16;
    return v.f;
}
__device__ inline float bfLo(unsigned u) {   // element at even index (low half)
    union { unsigned x; float f; } v; v.x = u << 16; return v.f;
}
__device__ inline float bfHi(unsigned u) {   // element at odd index (high half)
    union { unsigned x; float f; } v; v.x = u & 0xFFFF0000u; return v.f;
}

// ---------------- CSR build ----------------

__global__ void hist_kernel(const int* __restrict__ dst, int E, int* __restrict__ cnt) {
    int e = blockIdx.x * blockDim.x + threadIdx.x;
    if (e < E) atomicAdd(&cnt[dst[e]], 1);
}

__global__ void alloc_kernel(const int* __restrict__ cnt, int* __restrict__ row_start,
                             float* __restrict__ dinv, int* __restrict__ total, int N) {
    int i = blockIdx.x * blockDim.x + threadIdx.x;
    int lane = threadIdx.x & 63;
    int c = (i < N) ? cnt[i] : 0;
    int inc = c;
#pragma unroll
    for (int o = 1; o < 64; o <<= 1) {
        int v = __shfl_up(inc, o, 64);
        if (lane >= o) inc += v;
    }
    int wsum = __shfl(inc, 63, 64);
    int base = 0;
    if (lane == 0) base = atomicAdd(total, wsum);
    base = __shfl(base, 0, 64);
    if (i < N) {
        row_start[i] = base + inc - c;
        dinv[i] = rsqrtf((float)(c + 1));
    }
}

__global__ void scatter_kernel(const int* __restrict__ src, const int* __restrict__ dst, int E,
                               const int* __restrict__ row_start, int* __restrict__ cursor,
                               int* __restrict__ csr) {
    int e = blockIdx.x * blockDim.x + threadIdx.x;
    if (e < E) {
        int d = dst[e];
        int p = row_start[d] + atomicAdd(&cursor[d], 1);
        csr[p] = src[e];
    }
}

// ---------------- W1^T hi/lo split precompute: wt[n][k] bf16 ----------------
__global__ void wsplit_kernel(const float* __restrict__ W, ushort* __restrict__ wt_hi,
                              ushort* __restrict__ wt_lo) {
    int idx = blockIdx.x * blockDim.x + threadIdx.x;
    if (idx < 64 * 512) {
        int n = idx & 63, k = idx >> 6;           // read coalesced over n
        float f = W[k * 64 + n];
        ushort h = f2bf(f);
        wt_hi[n * 512 + k] = h;
        wt_lo[n * 512 + k] = f2bf(f - bf2f(h));
    }
}

// ---------------- GEMM1 (MFMA): p = dinv * (x @ W1) as bf16, hi/lo 3-term split ----------
__global__ __launch_bounds__(256, 3) void gemm1_kernel(const float* __restrict__ x,
                                                       const ushort* __restrict__ wt_hi,
                                                       const ushort* __restrict__ wt_lo,
                                                       const float* __restrict__ dinv,
                                                       ushort* __restrict__ out, int N) {
    __shared__ __align__(16) short xs_hi[128 * 64];   // 16 KB  [node][g'*8+j]
    __shared__ __align__(16) short xs_lo[128 * 64];   // 16 KB
    __shared__ __align__(16) short ws_hi[64 * 64];    //  8 KB  [n][g'*8+j]
    __shared__ __align__(16) short ws_lo[64 * 64];    //  8 KB

    const int tid = threadIdx.x;
    const int nodeBase = blockIdx.x * 128;
    const int wave = tid >> 6, lane = tid & 63;
    const int m16 = lane & 15, quad = lane >> 4;

    f32x4 acc[2][4];
#pragma unroll
    for (int mt = 0; mt < 2; mt++)
#pragma unroll
        for (int nt = 0; nt < 4; nt++) acc[mt][nt] = (f32x4){0.f, 0.f, 0.f, 0.f};

    for (int kc = 0; kc < 512; kc += 64) {
        __syncthreads();
#pragma unroll
        for (int i = 0; i < 4; i++) {
            int f = tid + i * 256;            // 0..1023
            int node = f >> 3, g = f & 7;
            int gn = nodeBase + node;
            if (gn >= N) gn = N - 1;
            const float4 a = *(const float4*)(x + (size_t)gn * 512 + kc + g * 8);
            const float4 b = *(const float4*)(x + (size_t)gn * 512 + kc + g * 8 + 4);
            float ff[8] = {a.x, a.y, a.z, a.w, b.x, b.y, b.z, b.w};
            union { ushort u[8]; uint4 v; } H, L;
#pragma unroll
            for (int j = 0; j < 8; j++) {
                ushort h = f2bf(ff[j]);
                H.u[j] = h;
                L.u[j] = f2bf(ff[j] - bf2f(h));
            }
            int gp = (g + node) & 7;
            *(uint4*)&xs_hi[node * 64 + gp * 8] = H.v;
            *(uint4*)&xs_lo[node * 64 + gp * 8] = L.v;
        }
#pragma unroll
        for (int i = 0; i < 2; i++) {
            int f = tid + i * 256;            // 0..511
            int n = f >> 3, g = f & 7;
            int gp = (g + n) & 7;
            *(uint4*)&ws_hi[n * 64 + gp * 8] =
                *(const uint4*)(wt_hi + (size_t)n * 512 + kc + g * 8);
            *(uint4*)&ws_lo[n * 64 + gp * 8] =
                *(const uint4*)(wt_lo + (size_t)n * 512 + kc + g * 8);
        }
        __syncthreads();
#pragma unroll
        for (int ck = 0; ck < 2; ck++) {
            s16x8 Ah[2], Al[2];
#pragma unroll
            for (int mt = 0; mt < 2; mt++) {
                int row = (wave * 2 + mt) * 16 + m16;     // local 0..127
                int gp = (ck * 4 + quad + row) & 7;
                Ah[mt] = *(s16x8*)&xs_hi[row * 64 + gp * 8];
                Al[mt] = *(s16x8*)&xs_lo[row * 64 + gp * 8];
            }
#pragma unroll
            for (int nt = 0; nt < 4; nt++) {
                int n = nt * 16 + m16;                    // local 0..63
                int gp = (ck * 4 + quad + n) & 7;
                s16x8 Bh = *(s16x8*)&ws_hi[n * 64 + gp * 8];
                s16x8 Bl = *(s16x8*)&ws_lo[n * 64 + gp * 8];
#pragma unroll
                for (int mt = 0; mt < 2; mt++) {
                    acc[mt][nt] = __builtin_amdgcn_mfma_f32_16x16x32_bf16(Ah[mt], Bh, acc[mt][nt], 0, 0, 0);
                    acc[mt][nt] = __builtin_amdgcn_mfma_f32_16x16x32_bf16(Ah[mt], Bl, acc[mt][nt], 0, 0, 0);
                    acc[mt][nt] = __builtin_amdgcn_mfma_f32_16x16x32_bf16(Al[mt], Bh, acc[mt][nt], 0, 0, 0);
                }
            }
        }
    }
    // C/D layout: col = lane&15, row = quad*4 + reg. Write p = dinv*acc as bf16.
#pragma unroll
    for (int mt = 0; mt < 2; mt++) {
#pragma unroll
        for (int r = 0; r < 4; r++) {
            int gn = nodeBase + (wave * 2 + mt) * 16 + quad * 4 + r;
            if (gn < N) {
                float di = dinv[gn];
#pragma unroll
                for (int nt = 0; nt < 4; nt++)
                    out[(size_t)gn * 64 + nt * 16 + m16] = f2bf(di * acc[mt][nt][r]);
            }
        }
    }
}

// ---------------- 64-dim CSR aggregation over premultiplied bf16 table ----------------
// out[i] = post( dinv[i] * (in[i] + sum_j in[j]) ), one wave per node, lane = feature.
template <int RELU, int BIAS, int PREMUL>
__global__ void agg64bf_kernel(const ushort* __restrict__ in, ushort* __restrict__ out,
                               const int* __restrict__ row_start, const int* __restrict__ cnt,
                               const int* __restrict__ csr, const float* __restrict__ dinv,
                               const float* __restrict__ bias, int N) {
    int gw = (int)((blockIdx.x * (size_t)blockDim.x + threadIdx.x) >> 6);
    int lane = threadIdx.x & 63;
    if (gw >= N) return;
    float acc = bf2f(in[(size_t)gw * 64 + lane]);   // self loop (already premultiplied)
    int s = row_start[gw];
    int c = cnt[gw];
    int e = 0;
    for (; e + 8 <= c; e += 8) {   // 8 gathers in flight
        int j0 = csr[s + e + 0], j1 = csr[s + e + 1], j2 = csr[s + e + 2], j3 = csr[s + e + 3];
        int j4 = csr[s + e + 4], j5 = csr[s + e + 5], j6 = csr[s + e + 6], j7 = csr[s + e + 7];
        float v0 = bf2f(in[(size_t)j0 * 64 + lane]);
        float v1 = bf2f(in[(size_t)j1 * 64 + lane]);
        float v2 = bf2f(in[(size_t)j2 * 64 + lane]);
        float v3 = bf2f(in[(size_t)j3 * 64 + lane]);
        float v4 = bf2f(in[(size_t)j4 * 64 + lane]);
        float v5 = bf2f(in[(size_t)j5 * 64 + lane]);
        float v6 = bf2f(in[(size_t)j6 * 64 + lane]);
        float v7 = bf2f(in[(size_t)j7 * 64 + lane]);
        acc += ((v0 + v1) + (v2 + v3)) + ((v4 + v5) + (v6 + v7));
    }
    for (; e < c; e++) {
        int j = csr[s + e];
        acc += bf2f(in[(size_t)j * 64 + lane]);
    }
    float di = dinv[gw];
    float v = di * acc;
    if (BIAS) v += bias[lane];
    if (RELU) v = fmaxf(v, 0.f);
    if (PREMUL) v *= di;
    out[(size_t)gw * 64 + lane] = f2bf(v);
}

// ---------------- fused GEMM2 (+bias,relu) + GEMM3: r = dinv * (relu(a2@W2+b2) @ W3) ----
__global__ __launch_bounds__(256, 2) void gemm23_kernel(const ushort* __restrict__ a2,
                                                        const float* __restrict__ W2,
                                                        const float* __restrict__ b2,
                                                        const float* __restrict__ W3,
                                                        const float* __restrict__ dinv,
                                                        float* __restrict__ r, int N) {
    __shared__ float w2s[64 * 256];
    __shared__ float b2s[256];
    __shared__ float w3s[256];
    const int tid = threadIdx.x;
#pragma unroll
    for (int i = 0; i < 16; i++) {
        int f4 = tid + i * 256;
        *(float4*)&w2s[f4 * 4] = *(const float4*)&W2[f4 * 4];
    }
    b2s[tid] = b2[tid];
    w3s[tid] = W3[tid];
    __syncthreads();

    const int lane = tid & 63;
    const int wave = tid >> 6;
    const int nodeBase = blockIdx.x * 64 + wave * 16;

    float4 w3f = *(const float4*)&w3s[lane * 4];
    float4 b2f = *(const float4*)&b2s[lane * 4];

    float acc[16][4];
#pragma unroll
    for (int n = 0; n < 16; n++) {
        acc[n][0] = 0.f; acc[n][1] = 0.f; acc[n][2] = 0.f; acc[n][3] = 0.f;
    }

    for (int k4 = 0; k4 < 64; k4 += 4) {
        float4 wf0 = *(const float4*)&w2s[(k4 + 0) * 256 + lane * 4];
        float4 wf1 = *(const float4*)&w2s[(k4 + 1) * 256 + lane * 4];
        float4 wf2 = *(const float4*)&w2s[(k4 + 2) * 256 + lane * 4];
        float4 wf3 = *(const float4*)&w2s[(k4 + 3) * 256 + lane * 4];
#pragma unroll
        for (int n = 0; n < 16; n++) {
            int gn = nodeBase + n;
            if (gn >= N) gn = N - 1;
            uint2 u = *(const uint2*)(a2 + (size_t)gn * 64 + k4);   // 4 bf16, uniform addr
            float a0 = bfLo(u.x), a1 = bfHi(u.x), a2v = bfLo(u.y), a3 = bfHi(u.y);
            acc[n][0] = fmaf(a0, wf0.x, acc[n][0]);
            acc[n][1] = fmaf(a0, wf0.y, acc[n][1]);
            acc[n][2] = fmaf(a0, wf0.z, acc[n][2]);
            acc[n][3] = fmaf(a0, wf0.w, acc[n][3]);
            acc[n][0] = fmaf(a1, wf1.x, acc[n][0]);
            acc[n][1] = fmaf(a1, wf1.y, acc[n][1]);
            acc[n][2] = fmaf(a1, wf1.z, acc[n][2]);
            acc[n][3] = fmaf(a1, wf1.w, acc[n][3]);
            acc[n][0] = fmaf(a2v, wf2.x, acc[n][0]);
            acc[n][1] = fmaf(a2v, wf2.y, acc[n][1]);
            acc[n][2] = fmaf(a2v, wf2.z, acc[n][2]);
            acc[n][3] = fmaf(a2v, wf2.w, acc[n][3]);
            acc[n][0] = fmaf(a3, wf3.x, acc[n][0]);
            acc[n][1] = fmaf(a3, wf3.y, acc[n][1]);
            acc[n][2] = fmaf(a3, wf3.z, acc[n][2]);
            acc[n][3] = fmaf(a3, wf3.w, acc[n][3]);
        }
    }

#pragma unroll
    for (int n = 0; n < 16; n++) {
        float r0 = fmaxf(acc[n][0] + b2f.x, 0.f);
        float r1 = fmaxf(acc[n][1] + b2f.y, 0.f);
        float r2 = fmaxf(acc[n][2] + b2f.z, 0.f);
        float r3 = fmaxf(acc[n][3] + b2f.w, 0.f);
        float p = r0 * w3f.x + r1 * w3f.y + r2 * w3f.z + r3 * w3f.w;
#pragma unroll
        for (int off = 32; off > 0; off >>= 1) p += __shfl_down(p, off, 64);
        int gn = nodeBase + n;
        if (lane == 0 && gn < N) r[gn] = dinv[gn] * p;
    }
}

// ---------------- scalar aggregation of premultiplied r + BCE loss + mean reduce --------
__global__ void loss_kernel(const float* __restrict__ r, const float* __restrict__ dinv,
                            const int* __restrict__ row_start, const int* __restrict__ cnt,
                            const int* __restrict__ csr, const float* __restrict__ y,
                            const float* __restrict__ b3, float* __restrict__ out,
                            int N, float invN) {
    int i = blockIdx.x * blockDim.x + threadIdx.x;
    float loss = 0.f;
    if (i < N) {
        float aedge = r[i];
        int s = row_start[i], c = cnt[i];
        int e = 0;
        for (; e + 4 <= c; e += 4) {
            int j0 = csr[s + e + 0], j1 = csr[s + e + 1];
            int j2 = csr[s + e + 2], j3 = csr[s + e + 3];
            aedge += (r[j0] + r[j1]) + (r[j2] + r[j3]);
        }
        for (; e < c; e++) aedge += r[csr[s + e]];
        float z = dinv[i] * aedge + b3[0];
        float yv = y[i];
        float L = log1pf(expf(-fabsf(z)));
        float spz  = fmaxf(z, 0.f) + L;    // softplus(z)
        float spnz = fmaxf(-z, 0.f) + L;   // softplus(-z)
        loss = yv * spnz + (1.f - yv) * spz;
    }
#pragma unroll
    for (int off = 32; off > 0; off >>= 1) loss += __shfl_down(loss, off, 64);
    __shared__ float red[4];
    int lane = threadIdx.x & 63, wave = threadIdx.x >> 6;
    if (lane == 0) red[wave] = loss;
    __syncthreads();
    if (threadIdx.x == 0)
        atomicAdd(out, (red[0] + red[1] + red[2] + red[3]) * invN);
}

// ---------------- launch ----------------
extern "C" void kernel_launch(void* const* d_in, const int* in_sizes, int n_in,
                              void* d_out, int out_size, void* d_ws, size_t ws_size,
                              hipStream_t stream) {
    const float* x  = (const float*)d_in[0];
    const int*   ei = (const int*)d_in[1];
    const float* y  = (const float*)d_in[2];
    const float* W1 = (const float*)d_in[3];
    const float* b1 = (const float*)d_in[4];
    const float* W2 = (const float*)d_in[5];
    const float* b2 = (const float*)d_in[6];
    const float* W3 = (const float*)d_in[7];
    const float* b3 = (const float*)d_in[8];

    const int N = in_sizes[2];        // y has N elements
    const int E = in_sizes[1] / 2;
    const int* src  = ei;
    const int* dstp = ei + E;

    char* w = (char*)d_ws;
    int*    cnt       = (int*)w;    w += (size_t)N * 4;
    int*    cursor    = (int*)w;    w += (size_t)N * 4;
    int*    total     = (int*)w;    w += 16;
    int*    row_start = (int*)w;    w += (size_t)N * 4;
    float*  dinv      = (float*)w;  w += (size_t)N * 4;
    int*    csr       = (int*)w;    w += (size_t)E * 4;
    ushort* wt_hi     = (ushort*)w; w += (size_t)64 * 512 * 2;
    ushort* wt_lo     = (ushort*)w; w += (size_t)64 * 512 * 2;
    ushort* pbuf      = (ushort*)w; w += (size_t)N * 64 * 2;   // p, later a2
    ushort* qbuf      = (ushort*)w; w += (size_t)N * 64 * 2;   // q
    float*  rbuf      = (float*)w;  w += (size_t)N * 4;        // r = dinv*t

    hipMemsetAsync(cnt, 0, (size_t)N * 8 + 16, stream);
    hipMemsetAsync(d_out, 0, sizeof(float), stream);

    const int tb = 256;
    wsplit_kernel<<<(64 * 512 + tb - 1) / tb, tb, 0, stream>>>(W1, wt_hi, wt_lo);
    hist_kernel<<<(E + tb - 1) / tb, tb, 0, stream>>>(dstp, E, cnt);
    alloc_kernel<<<(N + tb - 1) / tb, tb, 0, stream>>>(cnt, row_start, dinv, total, N);
    scatter_kernel<<<(E + tb - 1) / tb, tb, 0, stream>>>(src, dstp, E, row_start, cursor, csr);

    // layer 1: p = dinv * (x @ W1) as bf16
    gemm1_kernel<<<(N + 127) / 128, 256, 0, stream>>>(x, wt_hi, wt_lo, dinv, pbuf, N);
    // q = dinv * relu(dinv * (p_self + sum p_nbr) + b1)
    agg64bf_kernel<1, 1, 1><<<(N + 3) / 4, 256, 0, stream>>>(pbuf, qbuf, row_start, cnt, csr, dinv, b1, N);
    // a2 = dinv * (q_self + sum q_nbr)   (reuses pbuf)
    agg64bf_kernel<0, 0, 0><<<(N + 3) / 4, 256, 0, stream>>>(qbuf, pbuf, row_start, cnt, csr, dinv, nullptr, N);

    // layers 2+3 fused: r = dinv * (relu(a2 @ W2 + b2) @ W3)
    gemm23_kernel<<<(N + 63) / 64, 256, 0, stream>>>(pbuf, W2, b2, W3, dinv, rbuf, N);

    // layer 3 aggregation (scalar, premultiplied) + BCE + mean
    loss_kernel<<<(N + tb - 1) / tb, tb, 0, stream>>>(rbuf, dinv, row_start, cnt, csr, y, b3,
                                                      (float*)d_out, N, 1.0f / N);
}